// Round 6
// baseline (286.550 us; speedup 1.0000x reference)
//
#include <hip/hip_runtime.h>

typedef __bf16 bf16x8 __attribute__((ext_vector_type(8)));
typedef __bf16 bf16x4 __attribute__((ext_vector_type(4)));
typedef float f32x4 __attribute__((ext_vector_type(4)));
typedef float f32x16 __attribute__((ext_vector_type(16)));

#define D_MODEL 1024
#define NUM_HEADS 16
#define DK 64
#define BATCH 2
#define SEQ 2048
#define M_ROWS (BATCH*SEQ)

// (1/sqrt(DK)) * log2(e): folded into Q projection so attn uses exp2(z) raw
#define QSCALE 0.18033688011112042f

#if defined(__has_builtin)
#if __has_builtin(__builtin_amdgcn_exp2f)
#define EXP2(x) __builtin_amdgcn_exp2f(x)
#endif
#endif
#ifndef EXP2
#define EXP2(x) exp2f(x)
#endif

#define GLOAD_LDS16(gp, lp) __builtin_amdgcn_global_load_lds( \
    (__attribute__((address_space(1))) void*)(gp), \
    (__attribute__((address_space(3))) void*)(lp), 16, 0, 0)

#define ACT ((size_t)M_ROWS * D_MODEL)   // 4194304 = 2^22
#define WSZ ((size_t)D_MODEL * D_MODEL)  // 1048576 = 2^20

// One fused fp32->bf16 pass over all 7 tensors (dsts contiguous in ws):
// linear elem e in [0, 3*ACT + 4*WSZ = 2^24); region decode is shift/mask.
__global__ __launch_bounds__(256) void cvt_all(
    const float* __restrict__ q, const float* __restrict__ k,
    const float* __restrict__ v, const float* __restrict__ wq,
    const float* __restrict__ wk, const float* __restrict__ wv,
    const float* __restrict__ wo, __bf16* __restrict__ dst)
{
  size_t e = ((size_t)blockIdx.x * 256 + threadIdx.x) * 8;
  const float* s;
  size_t off;
  if (e < 3 * ACT) {
    int t = (int)(e >> 22);
    s = t == 0 ? q : (t == 1 ? k : v);
    off = e & (ACT - 1);
  } else {
    size_t e2 = e - 3 * ACT;
    int t = (int)(e2 >> 20);
    s = t == 0 ? wq : (t == 1 ? wk : (t == 2 ? wv : wo));
    off = e2 & (WSZ - 1);
  }
  float4 a = *(const float4*)(s + off);
  float4 b = *(const float4*)(s + off + 4);
  bf16x8 o;
  o[0] = (__bf16)a.x; o[1] = (__bf16)a.y; o[2] = (__bf16)a.z; o[3] = (__bf16)a.w;
  o[4] = (__bf16)b.x; o[5] = (__bf16)b.y; o[6] = (__bf16)b.z; o[7] = (__bf16)b.w;
  *(bf16x8*)(dst + e) = o;
}

// 128x128 GEMM tile, BK=64, XOR-swizzled LDS: row r's chunk j stored at
// chunk pos j^(r&7). Read bank base = 4*((J)^(l16&7)) -> uniform over 32
// banks (8 lanes/4-bank group = b128 inherent rate, no excess conflict).
template <typename OutT>
__device__ __forceinline__ void gemm_body(
    const __bf16* __restrict__ A, const __bf16* __restrict__ W,
    const float* __restrict__ bias, OutT* __restrict__ C,
    int M, int N, int K, int m0, int n0, float scale)
{
  __shared__ __align__(16) __bf16 sA[128*64];
  __shared__ __align__(16) __bf16 sB[128*64];
  const int tid  = threadIdx.x;
  const int wave = tid >> 6;
  const int lane = tid & 63;
  const int l16  = lane & 15;
  const int quad = lane >> 4;
  const int wm = (wave >> 1) * 64;
  const int wn = (wave & 1) * 64;

  f32x4 acc[4][4] = {};

  // staging: thread's lds slot c=i*256+tid holds row c>>3, chunk pos c&7;
  // source global chunk = (c&7)^((c>>3)&7) = (tid&7)^((tid>>3)&7) (i-invariant)
  const int gsw = (((tid & 7) ^ ((tid >> 3) & 7))) * 8;
  long aoff[4], boff[4];
#pragma unroll
  for (int i = 0; i < 4; i++) {
    int row = (i * 256 + tid) >> 3;
    aoff[i] = (long)(m0 + row) * K + gsw;
    boff[i] = (long)(n0 + row) * K + gsw;
  }
  const int rsw = l16 & 7;  // read swizzle selector (= row&7 for all frags)

  for (int k0 = 0; k0 < K; k0 += 64) {
    __syncthreads();
#pragma unroll
    for (int i = 0; i < 4; i++) {
      GLOAD_LDS16(A + aoff[i] + k0, (char*)sA + i * 4096 + wave * 1024);
      GLOAD_LDS16(W + boff[i] + k0, (char*)sB + i * 4096 + wave * 1024);
    }
    __syncthreads();
#pragma unroll
    for (int ks = 0; ks < 2; ks++) {
      bf16x8 af[4], bf[4];
#pragma unroll
      for (int i = 0; i < 4; i++)
        af[i] = *(const bf16x8*)&sA[(wm + i * 16 + l16) * 64 + ((ks * 4 + quad) ^ rsw) * 8];
#pragma unroll
      for (int j = 0; j < 4; j++)
        bf[j] = *(const bf16x8*)&sB[(wn + j * 16 + l16) * 64 + ((ks * 4 + quad) ^ rsw) * 8];
#pragma unroll
      for (int i = 0; i < 4; i++)
#pragma unroll
        for (int j = 0; j < 4; j++)
          acc[i][j] = __builtin_amdgcn_mfma_f32_16x16x32_bf16(af[i], bf[j], acc[i][j], 0, 0, 0);
    }
  }

#pragma unroll
  for (int j = 0; j < 4; j++) {
    int col = n0 + wn + j * 16 + l16;
    float bv = bias[col];
#pragma unroll
    for (int i = 0; i < 4; i++) {
      long row0 = m0 + wm + i * 16 + quad * 4;
#pragma unroll
      for (int r = 0; r < 4; r++)
        C[(row0 + r) * N + col] = (OutT)((acc[i][j][r] + bv) * scale);
    }
  }
}

__global__ __launch_bounds__(256) void gemm_qkv(
    const __bf16* __restrict__ Abase, const __bf16* __restrict__ Wbase,
    const float* __restrict__ b0, const float* __restrict__ b1,
    const float* __restrict__ b2, __bf16* __restrict__ Cbase)
{
  int z = blockIdx.z;
  const __bf16* A = Abase + (size_t)z * M_ROWS * D_MODEL;
  const __bf16* W = Wbase + (size_t)z * D_MODEL * D_MODEL;
  const float* bias = z == 0 ? b0 : (z == 1 ? b1 : b2);
  float scale = z == 0 ? QSCALE : 1.0f;  // fold softmax scale into Q
  __bf16* C = Cbase + (size_t)z * M_ROWS * D_MODEL;
  gemm_body<__bf16>(A, W, bias, C, M_ROWS, D_MODEL, D_MODEL,
                    blockIdx.y * 128, blockIdx.x * 128, scale);
}

__global__ __launch_bounds__(256) void gemm_out(
    const __bf16* __restrict__ A, const __bf16* __restrict__ W,
    const float* __restrict__ bias, float* __restrict__ C)
{
  gemm_body<float>(A, W, bias, C, M_ROWS, D_MODEL, D_MODEL,
                   blockIdx.y * 128, blockIdx.x * 128, 1.0f);
}

// Flash attention, no-max softmax, 32x32x16 MFMA.
// Block = 128 q-rows of one (b,h), 16 waves (1024 thr): wave = (qg = w&3,
// kh = w>>2) computes q-group qg (32 rows) x key-block kh (32 of 128/tile).
//
// R5 diagnosis: LDS-bandwidth-bound (16 FLOP/LDS-byte; ~40us of LDS service
// per CU). Fixes: (1) 32x32x16 MFMA doubles FLOP per operand byte;
// (2) K A-frags load straight from global/L2 (per-lane row = clean 16B
// loads) -- sK deleted entirely; (3) pi32 key permutation makes the S^T
// output the PV B-operand in-register (P never touches LDS); V staged at
// pi32-permuted columns. Net: 32 FLOP/LDS-byte, ~4x less LDS traffic.
// Per-wave lsum needs only shfl_xor(32); normalization is per-lane.
// O/lsum key-block partials combined once via LDS scratch epilogue.
//
// pi32 on each 32-key block: key k = r + 4*hi + 8*s (r=k[1:0], hi=k[2],
// s=k[4:3]) -> position p = (s&1)*16 + hi*8 + (s>>1)*4 + r. S^T reg i
// (C-layout row = (i&3)+8*(i>>2)+4*hb) lands at B-slot: kh2=(i>>2)&1,
// j=(i>>3)*4+(i&3); lane's hb bit matches the MFMA k-half natively.
__global__ __launch_bounds__(1024, 4) void attn_kernel(
    const __bf16* __restrict__ Q, const __bf16* __restrict__ K,
    const __bf16* __restrict__ V, __bf16* __restrict__ O)
{
  constexpr int SV_LD = 136;  // elems per d-row (128 cols + pad), 16B-aligned rows

  __shared__ __align__(16) __bf16 sVt[DK * SV_LD];   // [d][pi32(key)]
  __shared__ float oscr[12 * 32 * 64];               // kh>0 partials: [(kh-1)*4+qg][reg32][lane]
  __shared__ float lsb[16 * 32];                     // per-wave lsum[q]

  const int tid  = threadIdx.x;
  const int wave = tid >> 6;
  const int qg   = wave & 3;   // q-group (32 rows)
  const int kh   = wave >> 2;  // key-block (32 keys of the 128-key tile)
  const int lane = tid & 63;
  const int r32  = lane & 31;
  const int hb   = lane >> 5;

  const int bh = blockIdx.y;
  const int b  = bh >> 4, h = bh & (NUM_HEADS - 1);
  const int q0 = blockIdx.x * 128;
  const long base = (long)b * SEQ * D_MODEL + h * DK;

  // Q B-frags (register-resident): aq[m] = Q[q0+qg*32+r32][m*16 + hb*8 + j]
  const __bf16* qrow = Q + base + (long)(q0 + qg * 32 + r32) * D_MODEL + hb * 8;
  const bf16x8 aq0 = *(const bf16x8*)(qrow);
  const bf16x8 aq1 = *(const bf16x8*)(qrow + 16);
  const bf16x8 aq2 = *(const bf16x8*)(qrow + 32);
  const bf16x8 aq3 = *(const bf16x8*)(qrow + 48);

  // K A-frag pointer (direct from global, no LDS):
  // lane reads K[key = t*128 + kh*32 + r32][m*16 + hb*8 + j]
  const __bf16* kptr = K + base + (long)(kh * 32 + r32) * D_MODEL + hb * 8;

  // V staging (waves 0..7): lane owns key-pair (2*lane, 2*lane+1), d-group
  // wave*8. Destination column pi32-permuted; r=k[1:0] keeps pairs adjacent.
  const __bf16* vp0 = V + base + (long)(2 * lane) * D_MODEL + wave * 8;
  const int k5  = (2 * lane) & 31;
  const int p5  = ((k5 >> 3) & 1) * 16 + ((k5 >> 2) & 1) * 8 +
                  ((k5 >> 4) & 1) * 4 + (k5 & 3);
  const int vcol = (lane >> 4) * 16 + (p5 >> 1);  // packed-u32 column

  uint4 vr0, vr1;
  if (wave < 8) {
    vr0 = *(const uint4*)(vp0);
    vr1 = *(const uint4*)(vp0 + D_MODEL);
  }

  float lacc = 0.0f;
  f32x16 oa0 = {}, oa1 = {};  // O^T partial: d = da*32 + (i&3)+8*(i>>2)+4*hb, q = r32

  for (int t = 0; t < SEQ / 128; t++) {
    // issue this tile's K loads now; latency hides under barrier + V staging
    uint4 k0 = *(const uint4*)(kptr);
    uint4 k1 = *(const uint4*)(kptr + 16);
    uint4 k2 = *(const uint4*)(kptr + 32);
    uint4 k3 = *(const uint4*)(kptr + 48);
    kptr += 128 * D_MODEL;

    __syncthreads();  // previous tile's sVt reads done
    if (wave < 8) {
      const ushort* e0 = (const ushort*)&vr0;
      const ushort* e1 = (const ushort*)&vr1;
      uint* dst = (uint*)sVt;
#pragma unroll
      for (int j = 0; j < 8; j++)
        dst[(wave * 8 + j) * (SV_LD / 2) + vcol] = (uint)e0[j] | ((uint)e1[j] << 16);
      if (t + 1 < SEQ / 128) {
        long adv = (long)(t + 1) * 128 * D_MODEL;
        vr0 = *(const uint4*)(vp0 + adv);
        vr1 = *(const uint4*)(vp0 + adv + D_MODEL);
      }
    }
    __syncthreads();

    // S^T[32 key][32 q] = K Q^T over d=64: 4 MFMAs, A = K direct from regs
    f32x16 sacc = {};
    __builtin_amdgcn_s_setprio(1);
    sacc = __builtin_amdgcn_mfma_f32_32x32x16_bf16(*(const bf16x8*)&k0, aq0, sacc, 0, 0, 0);
    sacc = __builtin_amdgcn_mfma_f32_32x32x16_bf16(*(const bf16x8*)&k1, aq1, sacc, 0, 0, 0);
    sacc = __builtin_amdgcn_mfma_f32_32x32x16_bf16(*(const bf16x8*)&k2, aq2, sacc, 0, 0, 0);
    sacc = __builtin_amdgcn_mfma_f32_32x32x16_bf16(*(const bf16x8*)&k3, aq3, sacc, 0, 0, 0);
    __builtin_amdgcn_s_setprio(0);

    // softmax in-reg + pi32 pack into PV B-frags
    bf16x8 pb0, pb1;
#pragma unroll
    for (int i = 0; i < 16; i++) {
      float e = EXP2(sacc[i]);   // scale pre-folded in Q
      lacc += e;
      const int j = (i >> 3) * 4 + (i & 3);
      if (((i >> 2) & 1) == 0) pb0[j] = (__bf16)e;
      else                     pb1[j] = (__bf16)e;
    }

    // O^T += V^T P^T : A = V^T[d][pi-pos] from sVt, B = pb (in-register)
    const __bf16* vb = &sVt[r32 * SV_LD + kh * 32 + hb * 8];
    bf16x8 av00 = *(const bf16x8*)(vb);
    bf16x8 av01 = *(const bf16x8*)(vb + 16);
    bf16x8 av10 = *(const bf16x8*)(vb + 32 * SV_LD);
    bf16x8 av11 = *(const bf16x8*)(vb + 32 * SV_LD + 16);
    __builtin_amdgcn_s_setprio(1);
    oa0 = __builtin_amdgcn_mfma_f32_32x32x16_bf16(av00, pb0, oa0, 0, 0, 0);
    oa0 = __builtin_amdgcn_mfma_f32_32x32x16_bf16(av01, pb1, oa0, 0, 0, 0);
    oa1 = __builtin_amdgcn_mfma_f32_32x32x16_bf16(av10, pb0, oa1, 0, 0, 0);
    oa1 = __builtin_amdgcn_mfma_f32_32x32x16_bf16(av11, pb1, oa1, 0, 0, 0);
    __builtin_amdgcn_s_setprio(0);
  }

  // lane's q = r32. Combine hb-halves of its key-blocks:
  float ls = lacc + __shfl_xor(lacc, 32, 64);

  __syncthreads();  // last tile's sVt reads done; LDS reusable
  if (lane < 32) lsb[wave * 32 + lane] = ls;
  if (kh != 0) {
    float* sc = oscr + ((kh - 1) * 4 + qg) * (32 * 64);
#pragma unroll
    for (int i = 0; i < 16; i++) sc[i * 64 + lane] = oa0[i];
#pragma unroll
    for (int i = 0; i < 16; i++) sc[(16 + i) * 64 + lane] = oa1[i];
  }
  __syncthreads();
  if (kh == 0) {
    const int q = r32;
    float lst = lsb[qg * 32 + q] + lsb[(4 + qg) * 32 + q] +
                lsb[(8 + qg) * 32 + q] + lsb[(12 + qg) * 32 + q];
    float rls = 1.0f / lst;
    const long orow = base + (long)(q0 + qg * 32 + q) * D_MODEL;
#pragma unroll
    for (int da = 0; da < 2; da++) {
      f32x16 oo = da ? oa1 : oa0;
#pragma unroll
      for (int p = 0; p < 3; p++) {
        const float* sc = oscr + (p * 4 + qg) * (32 * 64) + da * 16 * 64;
#pragma unroll
        for (int i = 0; i < 16; i++) oo[i] += sc[i * 64 + lane];
      }
#pragma unroll
      for (int sg = 0; sg < 4; sg++) {
        bf16x4 ob;
#pragma unroll
        for (int r = 0; r < 4; r++) ob[r] = (__bf16)(oo[sg * 4 + r] * rls);
        int d0 = da * 32 + sg * 8 + hb * 4;
        *(bf16x4*)&O[orow + d0] = ob;
      }
    }
  }
}

extern "C" void kernel_launch(void* const* d_in, const int* in_sizes, int n_in,
                              void* d_out, int out_size, void* d_ws, size_t ws_size,
                              hipStream_t stream) {
  const float* q  = (const float*)d_in[0];
  const float* k  = (const float*)d_in[1];
  const float* v  = (const float*)d_in[2];
  const float* Wq = (const float*)d_in[3];
  const float* bq = (const float*)d_in[4];
  const float* Wk = (const float*)d_in[5];
  const float* bk = (const float*)d_in[6];
  const float* Wv = (const float*)d_in[7];
  const float* bv = (const float*)d_in[8];
  const float* Wo = (const float*)d_in[9];
  const float* bo = (const float*)d_in[10];
  float* out = (float*)d_out;

  __bf16* qc  = (__bf16*)d_ws;          // qc,kc,vc contiguous
  __bf16* Wqc = qc + 3 * ACT;           // Wq,Wk,Wv,Wo contiguous
  __bf16* wsQ = Wqc + 4 * WSZ;          // Q,K,V projections contiguous
  __bf16* wsAo = qc;                    // attn out reuses qc

  dim3 blk(256);
  // one fused cvt pass: 3*ACT + 4*WSZ = 2^24 elems, 8/thread
  cvt_all<<<dim3((3 * ACT + 4 * WSZ) / 2048), blk, 0, stream>>>(
      q, k, v, Wq, Wk, Wv, Wo, qc);

  gemm_qkv<<<dim3(D_MODEL / 128, M_ROWS / 128, 3), blk, 0, stream>>>(
      qc, Wqc, bq, bk, bv, wsQ);

  attn_kernel<<<dim3(SEQ / 128, BATCH * NUM_HEADS), dim3(1024), 0, stream>>>(
      wsQ, wsQ + ACT, wsQ + 2 * ACT, wsAo);

  gemm_out<<<dim3(D_MODEL / 128, M_ROWS / 128), blk, 0, stream>>>(
      wsAo, Wqc + 3 * WSZ, bo, out);
}

// Round 8
// 283.672 us; speedup vs baseline: 1.0101x; 1.0101x over previous
//
#include <hip/hip_runtime.h>

typedef __bf16 bf16x8 __attribute__((ext_vector_type(8)));
typedef __bf16 bf16x4 __attribute__((ext_vector_type(4)));
typedef float f32x4 __attribute__((ext_vector_type(4)));
typedef float f32x16 __attribute__((ext_vector_type(16)));

#define D_MODEL 1024
#define NUM_HEADS 16
#define DK 64
#define BATCH 2
#define SEQ 2048
#define M_ROWS (BATCH*SEQ)

// (1/sqrt(DK)) * log2(e): folded into Q projection so attn uses exp2(z) raw
#define QSCALE 0.18033688011112042f

#if defined(__has_builtin)
#if __has_builtin(__builtin_amdgcn_exp2f)
#define EXP2(x) __builtin_amdgcn_exp2f(x)
#endif
#endif
#ifndef EXP2
#define EXP2(x) exp2f(x)
#endif

#define GLOAD_LDS16(gp, lp) __builtin_amdgcn_global_load_lds( \
    (__attribute__((address_space(1))) void*)(gp), \
    (__attribute__((address_space(3))) void*)(lp), 16, 0, 0)

#define ACT ((size_t)M_ROWS * D_MODEL)   // 4194304 = 2^22
#define WSZ ((size_t)D_MODEL * D_MODEL)  // 1048576 = 2^20

// One fused fp32->bf16 pass over all 7 tensors (dsts contiguous in ws):
// linear elem e in [0, 3*ACT + 4*WSZ = 2^24); region decode is shift/mask.
__global__ __launch_bounds__(256) void cvt_all(
    const float* __restrict__ q, const float* __restrict__ k,
    const float* __restrict__ v, const float* __restrict__ wq,
    const float* __restrict__ wk, const float* __restrict__ wv,
    const float* __restrict__ wo, __bf16* __restrict__ dst)
{
  size_t e = ((size_t)blockIdx.x * 256 + threadIdx.x) * 8;
  const float* s;
  size_t off;
  if (e < 3 * ACT) {
    int t = (int)(e >> 22);
    s = t == 0 ? q : (t == 1 ? k : v);
    off = e & (ACT - 1);
  } else {
    size_t e2 = e - 3 * ACT;
    int t = (int)(e2 >> 20);
    s = t == 0 ? wq : (t == 1 ? wk : (t == 2 ? wv : wo));
    off = e2 & (WSZ - 1);
  }
  float4 a = *(const float4*)(s + off);
  float4 b = *(const float4*)(s + off + 4);
  bf16x8 o;
  o[0] = (__bf16)a.x; o[1] = (__bf16)a.y; o[2] = (__bf16)a.z; o[3] = (__bf16)a.w;
  o[4] = (__bf16)b.x; o[5] = (__bf16)b.y; o[6] = (__bf16)b.z; o[7] = (__bf16)b.w;
  *(bf16x8*)(dst + e) = o;
}

// 128x128 GEMM tile, BK=64, XOR-swizzled LDS: row r's chunk j stored at
// chunk pos j^(r&7). Read bank base = 4*((J)^(l16&7)) -> uniform over 32
// banks (8 lanes/4-bank group = b128 inherent rate, no excess conflict).
template <typename OutT>
__device__ __forceinline__ void gemm_body(
    const __bf16* __restrict__ A, const __bf16* __restrict__ W,
    const float* __restrict__ bias, OutT* __restrict__ C,
    int M, int N, int K, int m0, int n0, float scale)
{
  __shared__ __align__(16) __bf16 sA[128*64];
  __shared__ __align__(16) __bf16 sB[128*64];
  const int tid  = threadIdx.x;
  const int wave = tid >> 6;
  const int lane = tid & 63;
  const int l16  = lane & 15;
  const int quad = lane >> 4;
  const int wm = (wave >> 1) * 64;
  const int wn = (wave & 1) * 64;

  f32x4 acc[4][4] = {};

  // staging: thread's lds slot c=i*256+tid holds row c>>3, chunk pos c&7;
  // source global chunk = (c&7)^((c>>3)&7) = (tid&7)^((tid>>3)&7) (i-invariant)
  const int gsw = (((tid & 7) ^ ((tid >> 3) & 7))) * 8;
  long aoff[4], boff[4];
#pragma unroll
  for (int i = 0; i < 4; i++) {
    int row = (i * 256 + tid) >> 3;
    aoff[i] = (long)(m0 + row) * K + gsw;
    boff[i] = (long)(n0 + row) * K + gsw;
  }
  const int rsw = l16 & 7;  // read swizzle selector (= row&7 for all frags)

  for (int k0 = 0; k0 < K; k0 += 64) {
    __syncthreads();
#pragma unroll
    for (int i = 0; i < 4; i++) {
      GLOAD_LDS16(A + aoff[i] + k0, (char*)sA + i * 4096 + wave * 1024);
      GLOAD_LDS16(W + boff[i] + k0, (char*)sB + i * 4096 + wave * 1024);
    }
    __syncthreads();
#pragma unroll
    for (int ks = 0; ks < 2; ks++) {
      bf16x8 af[4], bf[4];
#pragma unroll
      for (int i = 0; i < 4; i++)
        af[i] = *(const bf16x8*)&sA[(wm + i * 16 + l16) * 64 + ((ks * 4 + quad) ^ rsw) * 8];
#pragma unroll
      for (int j = 0; j < 4; j++)
        bf[j] = *(const bf16x8*)&sB[(wn + j * 16 + l16) * 64 + ((ks * 4 + quad) ^ rsw) * 8];
#pragma unroll
      for (int i = 0; i < 4; i++)
#pragma unroll
        for (int j = 0; j < 4; j++)
          acc[i][j] = __builtin_amdgcn_mfma_f32_16x16x32_bf16(af[i], bf[j], acc[i][j], 0, 0, 0);
    }
  }

#pragma unroll
  for (int j = 0; j < 4; j++) {
    int col = n0 + wn + j * 16 + l16;
    float bv = bias[col];
#pragma unroll
    for (int i = 0; i < 4; i++) {
      long row0 = m0 + wm + i * 16 + quad * 4;
#pragma unroll
      for (int r = 0; r < 4; r++)
        C[(row0 + r) * N + col] = (OutT)((acc[i][j][r] + bv) * scale);
    }
  }
}

__global__ __launch_bounds__(256) void gemm_qkv(
    const __bf16* __restrict__ Abase, const __bf16* __restrict__ Wbase,
    const float* __restrict__ b0, const float* __restrict__ b1,
    const float* __restrict__ b2, __bf16* __restrict__ Cbase)
{
  int z = blockIdx.z;
  const __bf16* A = Abase + (size_t)z * M_ROWS * D_MODEL;
  const __bf16* W = Wbase + (size_t)z * D_MODEL * D_MODEL;
  const float* bias = z == 0 ? b0 : (z == 1 ? b1 : b2);
  float scale = z == 0 ? QSCALE : 1.0f;  // fold softmax scale into Q
  __bf16* C = Cbase + (size_t)z * M_ROWS * D_MODEL;
  gemm_body<__bf16>(A, W, bias, C, M_ROWS, D_MODEL, D_MODEL,
                    blockIdx.y * 128, blockIdx.x * 128, scale);
}

__global__ __launch_bounds__(256) void gemm_out(
    const __bf16* __restrict__ A, const __bf16* __restrict__ W,
    const float* __restrict__ bias, float* __restrict__ C)
{
  gemm_body<float>(A, W, bias, C, M_ROWS, D_MODEL, D_MODEL,
                   blockIdx.y * 128, blockIdx.x * 128, 1.0f);
}

// Flash attention, no-max softmax, 32x32x16 MFMA (math identical to R6,
// which verified: pi32 key permutation, K direct from global, in-register
// P, pair-packed V^T staging -- 0 bank conflicts, no spills).
//
// R6 regression diagnosis: (1) 98KB epilogue scratch -> 117KB LDS -> 1
// block/CU: one barrier domain, stragglers stall the whole CU; (2) t+1
// prefetch loads issued in the STAGING region, right before __syncthreads
// -> compiler's vmcnt(0) drain at the barrier exposes full HBM latency
// every tile with nothing to cover it.
//
// This version: block = 64 q, 4 waves (qg = w&1: 32-q group, kh = w>>1:
// 64-key half = 2 pi32 key-blocks). oscr 16KB -> LDS 34.3KB -> 4
// blocks/CU (4 barrier domains). Prefetch issue moved into the COMPUTE
// region: kb0's K(t+1) reload right after kb0's QK consumes the regs,
// kb1's K + V(t+1) after kb1's QK -- softmax+PV+staging hide the latency.
__global__ __launch_bounds__(256) void attn_kernel(
    const __bf16* __restrict__ Q, const __bf16* __restrict__ K,
    const __bf16* __restrict__ V, __bf16* __restrict__ O)
{
  constexpr int SV_LD = 136;  // elems per d-row (128 cols + pad)

  __shared__ __align__(16) __bf16 sVt[DK * SV_LD];  // [d][pi32(key)] 17.4KB
  __shared__ float oscr[2 * 32 * 64];               // kh=1 partials [qg][reg][lane] 16KB
  __shared__ float lsb[4 * 32];                     // per-wave lsum[q]

  const int tid  = threadIdx.x;
  const int wave = tid >> 6;
  const int qg   = wave & 1;   // q-group (32 rows)
  const int kh   = wave >> 1;  // key half (64 keys = 2 pi32 blocks)
  const int lane = tid & 63;
  const int r32  = lane & 31;
  const int hb   = lane >> 5;

  const int bh = blockIdx.y;
  const int b  = bh >> 4, h = bh & (NUM_HEADS - 1);
  const int q0 = blockIdx.x * 64;
  const long base = (long)b * SEQ * D_MODEL + h * DK;

  // Q B-frags (register-resident): aq[m] = Q[q0+qg*32+r32][m*16 + hb*8 + j]
  const __bf16* qrow = Q + base + (long)(q0 + qg * 32 + r32) * D_MODEL + hb * 8;
  const bf16x8 aq0 = *(const bf16x8*)(qrow);
  const bf16x8 aq1 = *(const bf16x8*)(qrow + 16);
  const bf16x8 aq2 = *(const bf16x8*)(qrow + 32);
  const bf16x8 aq3 = *(const bf16x8*)(qrow + 48);

  // K A-frag base (direct from global/L2, no LDS):
  // kb = kh*2 + j reads K[key = t*128 + kb*32 + r32][m*16 + hb*8 + jj]
  const __bf16* kptr = K + base + (long)(kh * 64 + r32) * D_MODEL + hb * 8;

  // V staging: lane owns key-pair (2*lane, 2*lane+1); wave owns d-group
  // [wave*16, wave*16+16). Destination column pi32-permuted (pairs adjacent):
  // p5 = (k[3])*16 + (k[2])*8 + (k[4])*4 + k[1:0]
  const __bf16* vp0 = V + base + (long)(2 * lane) * D_MODEL + wave * 16;
  const int k5 = (2 * lane) & 31;
  const int p5 = ((k5 >> 3) & 1) * 16 + ((k5 >> 2) & 1) * 8 +
                 ((k5 >> 4) & 1) * 4 + (k5 & 3);
  const int vcol = (lane >> 4) * 16 + (p5 >> 1);  // packed-u32 column

  // prologue prefetch: tile 0 (K: 8 frags for the wave's 2 key-blocks; V: 4)
  uint4 kr0, kr1, kr2, kr3, kr4, kr5, kr6, kr7, vr0, vr1, vr2, vr3;
  kr0 = *(const uint4*)(kptr);
  kr1 = *(const uint4*)(kptr + 16);
  kr2 = *(const uint4*)(kptr + 32);
  kr3 = *(const uint4*)(kptr + 48);
  kr4 = *(const uint4*)(kptr + 32 * D_MODEL);
  kr5 = *(const uint4*)(kptr + 32 * D_MODEL + 16);
  kr6 = *(const uint4*)(kptr + 32 * D_MODEL + 32);
  kr7 = *(const uint4*)(kptr + 32 * D_MODEL + 48);
  vr0 = *(const uint4*)(vp0);
  vr1 = *(const uint4*)(vp0 + 8);
  vr2 = *(const uint4*)(vp0 + D_MODEL);
  vr3 = *(const uint4*)(vp0 + D_MODEL + 8);

  float lacc = 0.0f;
  f32x16 oa0 = {}, oa1 = {};  // O^T partial: d = da*32+(i&3)+8*(i>>2)+4*hb, q = r32

  for (int t = 0; t < SEQ / 128; t++) {
    __syncthreads();  // previous tile's sVt reads done (drains our tile-t loads; needed now)
    // stage V transposed + pi32-permuted, pair-packed b32
    {
      const ushort* e0 = (const ushort*)&vr0;  // key 2l,   d w*16+0..7
      const ushort* e1 = (const ushort*)&vr1;  // key 2l,   d w*16+8..15
      const ushort* e2 = (const ushort*)&vr2;  // key 2l+1, d w*16+0..7
      const ushort* e3 = (const ushort*)&vr3;  // key 2l+1, d w*16+8..15
      uint* dst = (uint*)sVt;
#pragma unroll
      for (int j = 0; j < 8; j++) {
        dst[(wave * 16 + j) * (SV_LD / 2) + vcol] = (uint)e0[j] | ((uint)e2[j] << 16);
        dst[(wave * 16 + 8 + j) * (SV_LD / 2) + vcol] = (uint)e1[j] | ((uint)e3[j] << 16);
      }
    }
    __syncthreads();

    const long adv = (long)(t + 1) * 128 * D_MODEL;
    const bool more = (t + 1 < SEQ / 128);

    // ---- key-block kb0 = kh*2 ----
    {
      f32x16 sacc = {};
      __builtin_amdgcn_s_setprio(1);
      sacc = __builtin_amdgcn_mfma_f32_32x32x16_bf16(*(const bf16x8*)&kr0, aq0, sacc, 0, 0, 0);
      sacc = __builtin_amdgcn_mfma_f32_32x32x16_bf16(*(const bf16x8*)&kr1, aq1, sacc, 0, 0, 0);
      sacc = __builtin_amdgcn_mfma_f32_32x32x16_bf16(*(const bf16x8*)&kr2, aq2, sacc, 0, 0, 0);
      sacc = __builtin_amdgcn_mfma_f32_32x32x16_bf16(*(const bf16x8*)&kr3, aq3, sacc, 0, 0, 0);
      __builtin_amdgcn_s_setprio(0);
      // prefetch next tile's kb0 K-frags now (regs just freed); latency
      // hides under softmax+PV below -- issued in COMPUTE region, so the
      // barrier drain comes ~500cy later.
      if (more) {
        kr0 = *(const uint4*)(kptr + adv);
        kr1 = *(const uint4*)(kptr + adv + 16);
        kr2 = *(const uint4*)(kptr + adv + 32);
        kr3 = *(const uint4*)(kptr + adv + 48);
      }
      bf16x8 pb0, pb1;
#pragma unroll
      for (int i = 0; i < 16; i++) {
        float e = EXP2(sacc[i]);   // scale pre-folded in Q
        lacc += e;
        const int j = (i >> 3) * 4 + (i & 3);
        if (((i >> 2) & 1) == 0) pb0[j] = (__bf16)e;
        else                     pb1[j] = (__bf16)e;
      }
      const __bf16* vb = &sVt[r32 * SV_LD + (kh * 2) * 32 + hb * 8];
      bf16x8 av00 = *(const bf16x8*)(vb);
      bf16x8 av01 = *(const bf16x8*)(vb + 16);
      bf16x8 av10 = *(const bf16x8*)(vb + 32 * SV_LD);
      bf16x8 av11 = *(const bf16x8*)(vb + 32 * SV_LD + 16);
      __builtin_amdgcn_s_setprio(1);
      oa0 = __builtin_amdgcn_mfma_f32_32x32x16_bf16(av00, pb0, oa0, 0, 0, 0);
      oa0 = __builtin_amdgcn_mfma_f32_32x32x16_bf16(av01, pb1, oa0, 0, 0, 0);
      oa1 = __builtin_amdgcn_mfma_f32_32x32x16_bf16(av10, pb0, oa1, 0, 0, 0);
      oa1 = __builtin_amdgcn_mfma_f32_32x32x16_bf16(av11, pb1, oa1, 0, 0, 0);
      __builtin_amdgcn_s_setprio(0);
    }
    // ---- key-block kb1 = kh*2+1 ----
    {
      f32x16 sacc = {};
      __builtin_amdgcn_s_setprio(1);
      sacc = __builtin_amdgcn_mfma_f32_32x32x16_bf16(*(const bf16x8*)&kr4, aq0, sacc, 0, 0, 0);
      sacc = __builtin_amdgcn_mfma_f32_32x32x16_bf16(*(const bf16x8*)&kr5, aq1, sacc, 0, 0, 0);
      sacc = __builtin_amdgcn_mfma_f32_32x32x16_bf16(*(const bf16x8*)&kr6, aq2, sacc, 0, 0, 0);
      sacc = __builtin_amdgcn_mfma_f32_32x32x16_bf16(*(const bf16x8*)&kr7, aq3, sacc, 0, 0, 0);
      __builtin_amdgcn_s_setprio(0);
      if (more) {
        kr4 = *(const uint4*)(kptr + adv + 32 * D_MODEL);
        kr5 = *(const uint4*)(kptr + adv + 32 * D_MODEL + 16);
        kr6 = *(const uint4*)(kptr + adv + 32 * D_MODEL + 32);
        kr7 = *(const uint4*)(kptr + adv + 32 * D_MODEL + 48);
        vr0 = *(const uint4*)(vp0 + adv);
        vr1 = *(const uint4*)(vp0 + adv + 8);
        vr2 = *(const uint4*)(vp0 + adv + D_MODEL);
        vr3 = *(const uint4*)(vp0 + adv + D_MODEL + 8);
      }
      bf16x8 pb0, pb1;
#pragma unroll
      for (int i = 0; i < 16; i++) {
        float e = EXP2(sacc[i]);
        lacc += e;
        const int j = (i >> 3) * 4 + (i & 3);
        if (((i >> 2) & 1) == 0) pb0[j] = (__bf16)e;
        else                     pb1[j] = (__bf16)e;
      }
      const __bf16* vb = &sVt[r32 * SV_LD + (kh * 2 + 1) * 32 + hb * 8];
      bf16x8 av00 = *(const bf16x8*)(vb);
      bf16x8 av01 = *(const bf16x8*)(vb + 16);
      bf16x8 av10 = *(const bf16x8*)(vb + 32 * SV_LD);
      bf16x8 av11 = *(const bf16x8*)(vb + 32 * SV_LD + 16);
      __builtin_amdgcn_s_setprio(1);
      oa0 = __builtin_amdgcn_mfma_f32_32x32x16_bf16(av00, pb0, oa0, 0, 0, 0);
      oa0 = __builtin_amdgcn_mfma_f32_32x32x16_bf16(av01, pb1, oa0, 0, 0, 0);
      oa1 = __builtin_amdgcn_mfma_f32_32x32x16_bf16(av10, pb0, oa1, 0, 0, 0);
      oa1 = __builtin_amdgcn_mfma_f32_32x32x16_bf16(av11, pb1, oa1, 0, 0, 0);
      __builtin_amdgcn_s_setprio(0);
    }
  }

  // lane's q = r32. Combine hb halves of this wave's keys:
  float ls = lacc + __shfl_xor(lacc, 32, 64);

  __syncthreads();  // last tile's sVt reads done; LDS reusable
  if (lane < 32) lsb[wave * 32 + lane] = ls;
  if (kh == 1) {
    float* sc = oscr + qg * (32 * 64);
#pragma unroll
    for (int i = 0; i < 16; i++) sc[i * 64 + lane] = oa0[i];
#pragma unroll
    for (int i = 0; i < 16; i++) sc[(16 + i) * 64 + lane] = oa1[i];
  }
  __syncthreads();
  if (kh == 0) {
    const int q = r32;
    float lst = lsb[qg * 32 + q] + lsb[(2 + qg) * 32 + q];
    float rls = 1.0f / lst;
    const long orow = base + (long)(q0 + qg * 32 + q) * D_MODEL;
#pragma unroll
    for (int da = 0; da < 2; da++) {
      f32x16 oo = da ? oa1 : oa0;
      const float* sc = oscr + qg * (32 * 64) + da * 16 * 64;
#pragma unroll
      for (int i = 0; i < 16; i++) oo[i] += sc[i * 64 + lane];
#pragma unroll
      for (int sg = 0; sg < 4; sg++) {
        bf16x4 ob;
#pragma unroll
        for (int r = 0; r < 4; r++) ob[r] = (__bf16)(oo[sg * 4 + r] * rls);
        int d0 = da * 32 + sg * 8 + hb * 4;
        *(bf16x4*)&O[orow + d0] = ob;
      }
    }
  }
}

extern "C" void kernel_launch(void* const* d_in, const int* in_sizes, int n_in,
                              void* d_out, int out_size, void* d_ws, size_t ws_size,
                              hipStream_t stream) {
  const float* q  = (const float*)d_in[0];
  const float* k  = (const float*)d_in[1];
  const float* v  = (const float*)d_in[2];
  const float* Wq = (const float*)d_in[3];
  const float* bq = (const float*)d_in[4];
  const float* Wk = (const float*)d_in[5];
  const float* bk = (const float*)d_in[6];
  const float* Wv = (const float*)d_in[7];
  const float* bv = (const float*)d_in[8];
  const float* Wo = (const float*)d_in[9];
  const float* bo = (const float*)d_in[10];
  float* out = (float*)d_out;

  __bf16* qc  = (__bf16*)d_ws;          // qc,kc,vc contiguous
  __bf16* Wqc = qc + 3 * ACT;           // Wq,Wk,Wv,Wo contiguous
  __bf16* wsQ = Wqc + 4 * WSZ;          // Q,K,V projections contiguous
  __bf16* wsAo = qc;                    // attn out reuses qc

  dim3 blk(256);
  // one fused cvt pass: 3*ACT + 4*WSZ = 2^24 elems, 8/thread
  cvt_all<<<dim3((3 * ACT + 4 * WSZ) / 2048), blk, 0, stream>>>(
      q, k, v, Wq, Wk, Wv, Wo, qc);

  gemm_qkv<<<dim3(D_MODEL / 128, M_ROWS / 128, 3), blk, 0, stream>>>(
      qc, Wqc, bq, bk, bv, wsQ);

  attn_kernel<<<dim3(SEQ / 64, BATCH * NUM_HEADS), dim3(256), 0, stream>>>(
      wsQ, wsQ + ACT, wsQ + 2 * ACT, wsAo);

  gemm_out<<<dim3(D_MODEL / 128, M_ROWS / 128), blk, 0, stream>>>(
      wsAo, Wqc + 3 * WSZ, bo, out);
}

// Round 9
// 251.054 us; speedup vs baseline: 1.1414x; 1.1299x over previous
//
#include <hip/hip_runtime.h>

typedef __bf16 bf16x8 __attribute__((ext_vector_type(8)));
typedef __bf16 bf16x4 __attribute__((ext_vector_type(4)));
typedef float f32x4 __attribute__((ext_vector_type(4)));
typedef float f32x16 __attribute__((ext_vector_type(16)));

#define D_MODEL 1024
#define NUM_HEADS 16
#define DK 64
#define BATCH 2
#define SEQ 2048
#define M_ROWS (BATCH*SEQ)

// (1/sqrt(DK)) * log2(e): folded into Q projection so attn uses exp2(z) raw
#define QSCALE 0.18033688011112042f

#if defined(__has_builtin)
#if __has_builtin(__builtin_amdgcn_exp2f)
#define EXP2(x) __builtin_amdgcn_exp2f(x)
#endif
#endif
#ifndef EXP2
#define EXP2(x) exp2f(x)
#endif

#define GLOAD_LDS16(gp, lp) __builtin_amdgcn_global_load_lds( \
    (__attribute__((address_space(1))) void*)(gp), \
    (__attribute__((address_space(3))) void*)(lp), 16, 0, 0)

#define ACT ((size_t)M_ROWS * D_MODEL)   // 4194304 = 2^22
#define WSZ ((size_t)D_MODEL * D_MODEL)  // 1048576 = 2^20

// One fused fp32->bf16 pass over all 7 tensors (dsts contiguous in ws):
// linear elem e in [0, 3*ACT + 4*WSZ = 2^24); region decode is shift/mask.
__global__ __launch_bounds__(256) void cvt_all(
    const float* __restrict__ q, const float* __restrict__ k,
    const float* __restrict__ v, const float* __restrict__ wq,
    const float* __restrict__ wk, const float* __restrict__ wv,
    const float* __restrict__ wo, __bf16* __restrict__ dst)
{
  size_t e = ((size_t)blockIdx.x * 256 + threadIdx.x) * 8;
  const float* s;
  size_t off;
  if (e < 3 * ACT) {
    int t = (int)(e >> 22);
    s = t == 0 ? q : (t == 1 ? k : v);
    off = e & (ACT - 1);
  } else {
    size_t e2 = e - 3 * ACT;
    int t = (int)(e2 >> 20);
    s = t == 0 ? wq : (t == 1 ? wk : (t == 2 ? wv : wo));
    off = e2 & (WSZ - 1);
  }
  float4 a = *(const float4*)(s + off);
  float4 b = *(const float4*)(s + off + 4);
  bf16x8 o;
  o[0] = (__bf16)a.x; o[1] = (__bf16)a.y; o[2] = (__bf16)a.z; o[3] = (__bf16)a.w;
  o[4] = (__bf16)b.x; o[5] = (__bf16)b.y; o[6] = (__bf16)b.z; o[7] = (__bf16)b.w;
  *(bf16x8*)(dst + e) = o;
}

// 128x128 GEMM tile, BK=64, XOR-swizzled LDS: row r's chunk j stored at
// chunk pos j^(r&7). Read bank base = 4*((J)^(l16&7)) -> uniform over 32
// banks (8 lanes/4-bank group = b128 inherent rate, no excess conflict).
template <typename OutT>
__device__ __forceinline__ void gemm_body(
    const __bf16* __restrict__ A, const __bf16* __restrict__ W,
    const float* __restrict__ bias, OutT* __restrict__ C,
    int M, int N, int K, int m0, int n0, float scale)
{
  __shared__ __align__(16) __bf16 sA[128*64];
  __shared__ __align__(16) __bf16 sB[128*64];
  const int tid  = threadIdx.x;
  const int wave = tid >> 6;
  const int lane = tid & 63;
  const int l16  = lane & 15;
  const int quad = lane >> 4;
  const int wm = (wave >> 1) * 64;
  const int wn = (wave & 1) * 64;

  f32x4 acc[4][4] = {};

  // staging: thread's lds slot c=i*256+tid holds row c>>3, chunk pos c&7;
  // source global chunk = (c&7)^((c>>3)&7) = (tid&7)^((tid>>3)&7) (i-invariant)
  const int gsw = (((tid & 7) ^ ((tid >> 3) & 7))) * 8;
  long aoff[4], boff[4];
#pragma unroll
  for (int i = 0; i < 4; i++) {
    int row = (i * 256 + tid) >> 3;
    aoff[i] = (long)(m0 + row) * K + gsw;
    boff[i] = (long)(n0 + row) * K + gsw;
  }
  const int rsw = l16 & 7;  // read swizzle selector (= row&7 for all frags)

  for (int k0 = 0; k0 < K; k0 += 64) {
    __syncthreads();
#pragma unroll
    for (int i = 0; i < 4; i++) {
      GLOAD_LDS16(A + aoff[i] + k0, (char*)sA + i * 4096 + wave * 1024);
      GLOAD_LDS16(W + boff[i] + k0, (char*)sB + i * 4096 + wave * 1024);
    }
    __syncthreads();
#pragma unroll
    for (int ks = 0; ks < 2; ks++) {
      bf16x8 af[4], bf[4];
#pragma unroll
      for (int i = 0; i < 4; i++)
        af[i] = *(const bf16x8*)&sA[(wm + i * 16 + l16) * 64 + ((ks * 4 + quad) ^ rsw) * 8];
#pragma unroll
      for (int j = 0; j < 4; j++)
        bf[j] = *(const bf16x8*)&sB[(wn + j * 16 + l16) * 64 + ((ks * 4 + quad) ^ rsw) * 8];
#pragma unroll
      for (int i = 0; i < 4; i++)
#pragma unroll
        for (int j = 0; j < 4; j++)
          acc[i][j] = __builtin_amdgcn_mfma_f32_16x16x32_bf16(af[i], bf[j], acc[i][j], 0, 0, 0);
    }
  }

#pragma unroll
  for (int j = 0; j < 4; j++) {
    int col = n0 + wn + j * 16 + l16;
    float bv = bias[col];
#pragma unroll
    for (int i = 0; i < 4; i++) {
      long row0 = m0 + wm + i * 16 + quad * 4;
#pragma unroll
      for (int r = 0; r < 4; r++)
        C[(row0 + r) * N + col] = (OutT)((acc[i][j][r] + bv) * scale);
    }
  }
}

__global__ __launch_bounds__(256) void gemm_qkv(
    const __bf16* __restrict__ Abase, const __bf16* __restrict__ Wbase,
    const float* __restrict__ b0, const float* __restrict__ b1,
    const float* __restrict__ b2, __bf16* __restrict__ Cbase)
{
  int z = blockIdx.z;
  const __bf16* A = Abase + (size_t)z * M_ROWS * D_MODEL;
  const __bf16* W = Wbase + (size_t)z * D_MODEL * D_MODEL;
  const float* bias = z == 0 ? b0 : (z == 1 ? b1 : b2);
  float scale = z == 0 ? QSCALE : 1.0f;  // fold softmax scale into Q
  __bf16* C = Cbase + (size_t)z * M_ROWS * D_MODEL;
  gemm_body<__bf16>(A, W, bias, C, M_ROWS, D_MODEL, D_MODEL,
                    blockIdx.y * 128, blockIdx.x * 128, scale);
}

__global__ __launch_bounds__(256) void gemm_out(
    const __bf16* __restrict__ A, const __bf16* __restrict__ W,
    const float* __restrict__ bias, float* __restrict__ C)
{
  gemm_body<float>(A, W, bias, C, M_ROWS, D_MODEL, D_MODEL,
                   blockIdx.y * 128, blockIdx.x * 128, 1.0f);
}

// Flash attention, no-max softmax, 32x32x16 MFMA, pi32 key permutation
// (math verified R6/R8: in-register P, pair-packed V^T staging).
//
// R8 diagnosis: direct-from-global K A-frags are maximally UNCOALESCED --
// each lane reads 16B from a different 2KB-strided row, so one wave-load
// touches 64 cache lines; ~32k L2 line-transactions per block serialize at
// L2 latency (MfmaUtil 12.5, VALUBusy 25, HBM 9% -- all idle).
//
// This version: K staged COALESCED via global_load_lds (GEMM's proven
// pattern: pre-swizzled global source gsw, linear LDS dest), DOUBLE
// buffered -- DMA for t+1 issued right after barrier #2, drained a full
// compute phase later at the next barrier #1. K A-frags read from LDS with
// the XOR-swizzle b128 pattern (gemm-rate, conflict-free). V stays
// reg-staged (transpose needs per-lane rows), loads issued early in
// compute. Epilogue oscr ALIASES the sK double-buffer (dead by then):
// LDS = 32K(sKx2) + 17K(sVt) + 0.5K = 50.7KB -> 3 blocks/CU.
__global__ __launch_bounds__(256) void attn_kernel(
    const __bf16* __restrict__ Q, const __bf16* __restrict__ K,
    const __bf16* __restrict__ V, __bf16* __restrict__ O)
{
  constexpr int SV_LD = 136;  // elems per d-row (128 cols + pad)

  // LDS arena: [0,16K) sK buf0 (epilogue: oscr alias); [16K,32K) sK buf1;
  // [32K, +17408) sVt; then lsb.
  __shared__ __align__(16) char smem[32768 + DK * SV_LD * 2 + 4 * 32 * 4];
  __bf16* sKb0 = (__bf16*)(smem);
  __bf16* sKb1 = (__bf16*)(smem + 16384);
  __bf16* sVt  = (__bf16*)(smem + 32768);
  float*  lsb  = (float*)(smem + 32768 + DK * SV_LD * 2);
  float*  oscr = (float*)(smem);  // epilogue alias of sK buffers

  const int tid  = threadIdx.x;
  const int wave = tid >> 6;
  const int qg   = wave & 1;   // q-group (32 rows)
  const int kh   = wave >> 1;  // key half (64 keys = 2 pi32 blocks)
  const int lane = tid & 63;
  const int r32  = lane & 31;
  const int hb   = lane >> 5;

  const int bh = blockIdx.y;
  const int b  = bh >> 4, h = bh & (NUM_HEADS - 1);
  const int q0 = blockIdx.x * 64;
  const long base = (long)b * SEQ * D_MODEL + h * DK;

  // Q B-frags (register-resident): aq[m] = Q[q0+qg*32+r32][m*16 + hb*8 + j]
  const __bf16* qrow = Q + base + (long)(q0 + qg * 32 + r32) * D_MODEL + hb * 8;
  const bf16x8 aq0 = *(const bf16x8*)(qrow);
  const bf16x8 aq1 = *(const bf16x8*)(qrow + 16);
  const bf16x8 aq2 = *(const bf16x8*)(qrow + 32);
  const bf16x8 aq3 = *(const bf16x8*)(qrow + 48);

  // K staging (coalesced, gemm-style): thread slot c = i*256+tid holds
  // row c>>3, chunk pos c&7; source global chunk = (tid&7)^((tid>>3)&7).
  const int gsw = (((tid & 7) ^ ((tid >> 3) & 7))) * 8;
  const __bf16* kgp = K + base + (long)(tid >> 3) * D_MODEL + gsw;
  const int asw = r32 & 7;  // A-frag read swizzle (= row&7)

  // V staging: lane owns key-pair (2*lane, 2*lane+1); wave owns d-group
  // [wave*16, wave*16+16). Destination column pi32-permuted (pairs adjacent):
  // p5 = (k[3])*16 + (k[2])*8 + (k[4])*4 + k[1:0]
  const __bf16* vp0 = V + base + (long)(2 * lane) * D_MODEL + wave * 16;
  const int k5 = (2 * lane) & 31;
  const int p5 = ((k5 >> 3) & 1) * 16 + ((k5 >> 2) & 1) * 8 +
                 ((k5 >> 4) & 1) * 4 + (k5 & 3);
  const int vcol = (lane >> 4) * 16 + (p5 >> 1);  // packed-u32 column

  // prologue: issue tile-0 K DMA into buf0; load tile-0 V regs
#pragma unroll
  for (int i = 0; i < 4; i++)
    GLOAD_LDS16(kgp + (long)i * 32 * D_MODEL, (char*)sKb0 + i * 4096 + tid * 16);
  uint4 vr0 = *(const uint4*)(vp0);
  uint4 vr1 = *(const uint4*)(vp0 + 8);
  uint4 vr2 = *(const uint4*)(vp0 + D_MODEL);
  uint4 vr3 = *(const uint4*)(vp0 + D_MODEL + 8);

  float lacc = 0.0f;
  f32x16 oa0 = {}, oa1 = {};  // O^T partial: d = da*32+(i&3)+8*(i>>2)+4*hb, q = r32

  int buf = 0;
  for (int t = 0; t < SEQ / 128; t++) {
    __syncthreads();  // prev compute done; K-DMA(t) + vr(t) drained here
    // stage V transposed + pi32-permuted, pair-packed b32
    {
      const ushort* e0 = (const ushort*)&vr0;  // key 2l,   d w*16+0..7
      const ushort* e1 = (const ushort*)&vr1;  // key 2l,   d w*16+8..15
      const ushort* e2 = (const ushort*)&vr2;  // key 2l+1, d w*16+0..7
      const ushort* e3 = (const ushort*)&vr3;  // key 2l+1, d w*16+8..15
      uint* dst = (uint*)sVt;
#pragma unroll
      for (int j = 0; j < 8; j++) {
        dst[(wave * 16 + j) * (SV_LD / 2) + vcol] = (uint)e0[j] | ((uint)e2[j] << 16);
        dst[(wave * 16 + 8 + j) * (SV_LD / 2) + vcol] = (uint)e1[j] | ((uint)e3[j] << 16);
      }
    }
    __syncthreads();  // sVt(t) + sK(t) visible

    const long adv = (long)(t + 1) * 128 * D_MODEL;
    const bool more = (t + 1 < SEQ / 128);
    const __bf16* sKc = buf ? sKb1 : sKb0;
    char* sKn = (char*)(buf ? sKb0 : sKb1);

    // issue next tile's K DMA into the OTHER buffer: drains at the next
    // barrier #1, a full compute phase (~700cy) away.
    if (more) {
#pragma unroll
      for (int i = 0; i < 4; i++)
        GLOAD_LDS16(kgp + adv + (long)i * 32 * D_MODEL, sKn + i * 4096 + tid * 16);
    }

    // ---- key-block kb0 = kh*2 (LDS rows kh*64 + r32) ----
    {
      bf16x8 ka0 = *(const bf16x8*)&sKc[(kh * 64 + r32) * 64 + ((hb + 0) ^ asw) * 8];
      bf16x8 ka1 = *(const bf16x8*)&sKc[(kh * 64 + r32) * 64 + ((hb + 2) ^ asw) * 8];
      bf16x8 ka2 = *(const bf16x8*)&sKc[(kh * 64 + r32) * 64 + ((hb + 4) ^ asw) * 8];
      bf16x8 ka3 = *(const bf16x8*)&sKc[(kh * 64 + r32) * 64 + ((hb + 6) ^ asw) * 8];
      f32x16 sacc = {};
      __builtin_amdgcn_s_setprio(1);
      sacc = __builtin_amdgcn_mfma_f32_32x32x16_bf16(ka0, aq0, sacc, 0, 0, 0);
      sacc = __builtin_amdgcn_mfma_f32_32x32x16_bf16(ka1, aq1, sacc, 0, 0, 0);
      sacc = __builtin_amdgcn_mfma_f32_32x32x16_bf16(ka2, aq2, sacc, 0, 0, 0);
      sacc = __builtin_amdgcn_mfma_f32_32x32x16_bf16(ka3, aq3, sacc, 0, 0, 0);
      __builtin_amdgcn_s_setprio(0);
      // early-issue next tile's V loads (uncoalesced; long latency) --
      // consumed at next iter's stage-V, drained at next barrier #1.
      if (more) {
        vr0 = *(const uint4*)(vp0 + adv);
        vr1 = *(const uint4*)(vp0 + adv + 8);
        vr2 = *(const uint4*)(vp0 + adv + D_MODEL);
        vr3 = *(const uint4*)(vp0 + adv + D_MODEL + 8);
      }
      bf16x8 pb0, pb1;
#pragma unroll
      for (int i = 0; i < 16; i++) {
        float e = EXP2(sacc[i]);   // scale pre-folded in Q
        lacc += e;
        const int j = (i >> 3) * 4 + (i & 3);
        if (((i >> 2) & 1) == 0) pb0[j] = (__bf16)e;
        else                     pb1[j] = (__bf16)e;
      }
      const __bf16* vb = &sVt[r32 * SV_LD + (kh * 2) * 32 + hb * 8];
      bf16x8 av00 = *(const bf16x8*)(vb);
      bf16x8 av01 = *(const bf16x8*)(vb + 16);
      bf16x8 av10 = *(const bf16x8*)(vb + 32 * SV_LD);
      bf16x8 av11 = *(const bf16x8*)(vb + 32 * SV_LD + 16);
      __builtin_amdgcn_s_setprio(1);
      oa0 = __builtin_amdgcn_mfma_f32_32x32x16_bf16(av00, pb0, oa0, 0, 0, 0);
      oa0 = __builtin_amdgcn_mfma_f32_32x32x16_bf16(av01, pb1, oa0, 0, 0, 0);
      oa1 = __builtin_amdgcn_mfma_f32_32x32x16_bf16(av10, pb0, oa1, 0, 0, 0);
      oa1 = __builtin_amdgcn_mfma_f32_32x32x16_bf16(av11, pb1, oa1, 0, 0, 0);
      __builtin_amdgcn_s_setprio(0);
    }
    // ---- key-block kb1 = kh*2+1 (LDS rows kh*64 + 32 + r32) ----
    {
      bf16x8 ka0 = *(const bf16x8*)&sKc[(kh * 64 + 32 + r32) * 64 + ((hb + 0) ^ asw) * 8];
      bf16x8 ka1 = *(const bf16x8*)&sKc[(kh * 64 + 32 + r32) * 64 + ((hb + 2) ^ asw) * 8];
      bf16x8 ka2 = *(const bf16x8*)&sKc[(kh * 64 + 32 + r32) * 64 + ((hb + 4) ^ asw) * 8];
      bf16x8 ka3 = *(const bf16x8*)&sKc[(kh * 64 + 32 + r32) * 64 + ((hb + 6) ^ asw) * 8];
      f32x16 sacc = {};
      __builtin_amdgcn_s_setprio(1);
      sacc = __builtin_amdgcn_mfma_f32_32x32x16_bf16(ka0, aq0, sacc, 0, 0, 0);
      sacc = __builtin_amdgcn_mfma_f32_32x32x16_bf16(ka1, aq1, sacc, 0, 0, 0);
      sacc = __builtin_amdgcn_mfma_f32_32x32x16_bf16(ka2, aq2, sacc, 0, 0, 0);
      sacc = __builtin_amdgcn_mfma_f32_32x32x16_bf16(ka3, aq3, sacc, 0, 0, 0);
      __builtin_amdgcn_s_setprio(0);
      bf16x8 pb0, pb1;
#pragma unroll
      for (int i = 0; i < 16; i++) {
        float e = EXP2(sacc[i]);
        lacc += e;
        const int j = (i >> 3) * 4 + (i & 3);
        if (((i >> 2) & 1) == 0) pb0[j] = (__bf16)e;
        else                     pb1[j] = (__bf16)e;
      }
      const __bf16* vb = &sVt[r32 * SV_LD + (kh * 2 + 1) * 32 + hb * 8];
      bf16x8 av00 = *(const bf16x8*)(vb);
      bf16x8 av01 = *(const bf16x8*)(vb + 16);
      bf16x8 av10 = *(const bf16x8*)(vb + 32 * SV_LD);
      bf16x8 av11 = *(const bf16x8*)(vb + 32 * SV_LD + 16);
      __builtin_amdgcn_s_setprio(1);
      oa0 = __builtin_amdgcn_mfma_f32_32x32x16_bf16(av00, pb0, oa0, 0, 0, 0);
      oa0 = __builtin_amdgcn_mfma_f32_32x32x16_bf16(av01, pb1, oa0, 0, 0, 0);
      oa1 = __builtin_amdgcn_mfma_f32_32x32x16_bf16(av10, pb0, oa1, 0, 0, 0);
      oa1 = __builtin_amdgcn_mfma_f32_32x32x16_bf16(av11, pb1, oa1, 0, 0, 0);
      __builtin_amdgcn_s_setprio(0);
    }
    buf ^= 1;
  }

  // lane's q = r32. Combine hb halves of this wave's keys:
  float ls = lacc + __shfl_xor(lacc, 32, 64);

  __syncthreads();  // last tile's LDS reads done; sK arena reusable as oscr
  if (lane < 32) lsb[wave * 32 + lane] = ls;
  if (kh == 1) {
    float* sc = oscr + qg * (32 * 64);
#pragma unroll
    for (int i = 0; i < 16; i++) sc[i * 64 + lane] = oa0[i];
#pragma unroll
    for (int i = 0; i < 16; i++) sc[(16 + i) * 64 + lane] = oa1[i];
  }
  __syncthreads();
  if (kh == 0) {
    const int q = r32;
    float lst = lsb[qg * 32 + q] + lsb[(2 + qg) * 32 + q];
    float rls = 1.0f / lst;
    const long orow = base + (long)(q0 + qg * 32 + q) * D_MODEL;
#pragma unroll
    for (int da = 0; da < 2; da++) {
      f32x16 oo = da ? oa1 : oa0;
      const float* sc = oscr + qg * (32 * 64) + da * 16 * 64;
#pragma unroll
      for (int i = 0; i < 16; i++) oo[i] += sc[i * 64 + lane];
#pragma unroll
      for (int sg = 0; sg < 4; sg++) {
        bf16x4 ob;
#pragma unroll
        for (int r = 0; r < 4; r++) ob[r] = (__bf16)(oo[sg * 4 + r] * rls);
        int d0 = da * 32 + sg * 8 + hb * 4;
        *(bf16x4*)&O[orow + d0] = ob;
      }
    }
  }
}

extern "C" void kernel_launch(void* const* d_in, const int* in_sizes, int n_in,
                              void* d_out, int out_size, void* d_ws, size_t ws_size,
                              hipStream_t stream) {
  const float* q  = (const float*)d_in[0];
  const float* k  = (const float*)d_in[1];
  const float* v  = (const float*)d_in[2];
  const float* Wq = (const float*)d_in[3];
  const float* bq = (const float*)d_in[4];
  const float* Wk = (const float*)d_in[5];
  const float* bk = (const float*)d_in[6];
  const float* Wv = (const float*)d_in[7];
  const float* bv = (const float*)d_in[8];
  const float* Wo = (const float*)d_in[9];
  const float* bo = (const float*)d_in[10];
  float* out = (float*)d_out;

  __bf16* qc  = (__bf16*)d_ws;          // qc,kc,vc contiguous
  __bf16* Wqc = qc + 3 * ACT;           // Wq,Wk,Wv,Wo contiguous
  __bf16* wsQ = Wqc + 4 * WSZ;          // Q,K,V projections contiguous
  __bf16* wsAo = qc;                    // attn out reuses qc

  dim3 blk(256);
  // one fused cvt pass: 3*ACT + 4*WSZ = 2^24 elems, 8/thread
  cvt_all<<<dim3((3 * ACT + 4 * WSZ) / 2048), blk, 0, stream>>>(
      q, k, v, Wq, Wk, Wv, Wo, qc);

  gemm_qkv<<<dim3(D_MODEL / 128, M_ROWS / 128, 3), blk, 0, stream>>>(
      qc, Wqc, bq, bk, bv, wsQ);

  attn_kernel<<<dim3(SEQ / 64, BATCH * NUM_HEADS), dim3(256), 0, stream>>>(
      wsQ, wsQ + ACT, wsQ + 2 * ACT, wsAo);

  gemm_out<<<dim3(D_MODEL / 128, M_ROWS / 128), blk, 0, stream>>>(
      wsAo, Wqc + 3 * WSZ, bo, out);
}